// Round 16
// baseline (222.939 us; speedup 1.0000x reference)
//
#include <hip/hip_runtime.h>
#include <hip/hip_bf16.h>
#include <cmath>

typedef __bf16 bf16_t;
typedef __bf16 bf16x8 __attribute__((ext_vector_type(8)));
typedef __bf16 bf16x4 __attribute__((ext_vector_type(4)));
typedef float f32x4 __attribute__((ext_vector_type(4)));

#define AS1 __attribute__((address_space(1)))
#define AS3 __attribute__((address_space(3)))

__device__ __forceinline__ void async_lds16(const void* g, void* s) {
    __builtin_amdgcn_global_load_lds((const AS1 void*)g, (AS3 void*)s, 16, 0, 0);
}

__device__ __forceinline__ float bf2f(bf16_t v) { return (float)v; }

// XCD chunking + 4x4 supertile decode (kept: -33% FETCH)
__device__ __forceinline__ void tile_coords(int gx, int gy, int& mb, int& nb) {
    const int nwg = gx * gy;
    int lin = blockIdx.y * gx + blockIdx.x;
    if ((nwg & 7) == 0) lin = (lin & 7) * (nwg >> 3) + (lin >> 3);
    if ((gx & 3) == 0 && (gy & 3) == 0) {
        const int st = lin >> 4, pos = lin & 15;
        const int stn = gx >> 2;
        mb = (st / stn) * 4 + (pos >> 2);
        nb = (st % stn) * 4 + (pos & 3);
    } else {
        mb = lin / gx; nb = lin % gx;
    }
}

// ---------------- Wq/Wk/Wv transposes + LN1 (7168 blocks)
// b<3072: Wq/Wk/Wv (1024x1024); else LN1 row (b-3072)
__global__ __launch_bounds__(256) void k_prep(
    const float* __restrict__ s0, const float* __restrict__ s1,
    const float* __restrict__ s2,
    bf16_t* __restrict__ d0, bf16_t* __restrict__ d1, bf16_t* __restrict__ d2,
    const float* __restrict__ x, const float* __restrict__ g,
    const float* __restrict__ bln, bf16_t* __restrict__ hout) {
    const int b = blockIdx.x;
    const int t = threadIdx.x;
    if (b >= 3072) {  // LN1 row
        const int row = b - 3072;
        const float4 xv = reinterpret_cast<const float4*>(x + (size_t)row * 1024)[t];
        float s = xv.x + xv.y + xv.z + xv.w;
        float s2 = xv.x * xv.x + xv.y * xv.y + xv.z * xv.z + xv.w * xv.w;
#pragma unroll
        for (int mk = 32; mk >= 1; mk >>= 1) {
            s += __shfl_xor(s, mk);
            s2 += __shfl_xor(s2, mk);
        }
        __shared__ float red[8];
        const int w = t >> 6, l = t & 63;
        if (l == 0) { red[w] = s; red[4 + w] = s2; }
        __syncthreads();
        s = red[0] + red[1] + red[2] + red[3];
        s2 = red[4] + red[5] + red[6] + red[7];
        const float mu = s * (1.0f / 1024.0f);
        const float var = s2 * (1.0f / 1024.0f) - mu * mu;
        const float rs = rsqrtf(var + 1e-5f);
        const float4 gv = reinterpret_cast<const float4*>(g)[t];
        const float4 bv = reinterpret_cast<const float4*>(bln)[t];
        bf16x4 o4;
        o4[0] = (bf16_t)((xv.x - mu) * rs * gv.x + bv.x);
        o4[1] = (bf16_t)((xv.y - mu) * rs * gv.y + bv.y);
        o4[2] = (bf16_t)((xv.z - mu) * rs * gv.z + bv.z);
        o4[3] = (bf16_t)((xv.w - mu) * rs * gv.w + bv.w);
        *reinterpret_cast<bf16x4*>(hout + (size_t)row * 1024 + t * 4) = o4;
        return;
    }
    const int m = b >> 10;
    const int tile = b & 1023;
    const float* src = m == 0 ? s0 : m == 1 ? s1 : s2;
    bf16_t* dst = m == 0 ? d0 : m == 1 ? d1 : d2;
    const int r0 = (tile >> 5) << 5, c0 = (tile & 31) << 5;
    __shared__ float tl[32][33];
    const int tx = t & 31, ty = t >> 5;
#pragma unroll
    for (int i = 0; i < 32; i += 8)
        tl[ty + i][tx] = src[(size_t)(r0 + ty + i) * 1024 + c0 + tx];
    __syncthreads();
#pragma unroll
    for (int i = 0; i < 32; i += 8)
        dst[(size_t)(c0 + ty + i) * 1024 + r0 + tx] = (bf16_t)tl[tx][ty + i];
}

// ---------------- 4x bf16 partial reduce + bias + residual + fused LN
__global__ __launch_bounds__(256) void k_reduce_ln4(
    const bf16_t* __restrict__ pp,
    const float* __restrict__ bo, const float* __restrict__ x,
    const float* __restrict__ g, const float* __restrict__ b,
    bf16_t* __restrict__ x2, bf16_t* __restrict__ m2, long long zs) {
    const int row = blockIdx.x;
    const int t = threadIdx.x;
    const size_t off = (size_t)row * 1024 + t * 4;
    const float4 bb = reinterpret_cast<const float4*>(bo)[t];
    const float4 xv = *reinterpret_cast<const float4*>(x + off);
    float4 v;
    v.x = bb.x + xv.x; v.y = bb.y + xv.y; v.z = bb.z + xv.z; v.w = bb.w + xv.w;
#pragma unroll
    for (int z = 0; z < 4; z++) {
        const bf16x4 p = *reinterpret_cast<const bf16x4*>(pp + z * zs + off);
        v.x += bf2f(p[0]); v.y += bf2f(p[1]); v.z += bf2f(p[2]); v.w += bf2f(p[3]);
    }
    bf16x4 xo;
    xo[0] = (bf16_t)v.x; xo[1] = (bf16_t)v.y; xo[2] = (bf16_t)v.z; xo[3] = (bf16_t)v.w;
    *reinterpret_cast<bf16x4*>(x2 + off) = xo;
    float s = v.x + v.y + v.z + v.w;
    float s2 = v.x * v.x + v.y * v.y + v.z * v.z + v.w * v.w;
#pragma unroll
    for (int mk = 32; mk >= 1; mk >>= 1) {
        s += __shfl_xor(s, mk);
        s2 += __shfl_xor(s2, mk);
    }
    __shared__ float red[8];
    const int w = t >> 6, l = t & 63;
    if (l == 0) { red[w] = s; red[4 + w] = s2; }
    __syncthreads();
    s = red[0] + red[1] + red[2] + red[3];
    s2 = red[4] + red[5] + red[6] + red[7];
    const float mu = s * (1.0f / 1024.0f);
    const float var = s2 * (1.0f / 1024.0f) - mu * mu;
    const float rs = rsqrtf(var + 1e-5f);
    const float4 gv = reinterpret_cast<const float4*>(g)[t];
    const float4 bv = reinterpret_cast<const float4*>(b)[t];
    bf16x4 o4;
    o4[0] = (bf16_t)((v.x - mu) * rs * gv.x + bv.x);
    o4[1] = (bf16_t)((v.y - mu) * rs * gv.y + bv.y);
    o4[2] = (bf16_t)((v.z - mu) * rs * gv.z + bv.z);
    o4[3] = (bf16_t)((v.w - mu) * rs * gv.w + bv.w);
    *reinterpret_cast<bf16x4*>(m2 + off) = o4;
}

// ---------------- final reduce: d_out = pA(2) + pB(2) + b2 + x2(bf16)
__global__ __launch_bounds__(256) void k_reduce_out4(
    const bf16_t* __restrict__ pA, const bf16_t* __restrict__ pB,
    const float* __restrict__ b2, const bf16_t* __restrict__ x2,
    float* __restrict__ outp, long long zs) {
    const size_t off = ((size_t)blockIdx.x * 256 + threadIdx.x) * 4;
    const bf16x4 c = *reinterpret_cast<const bf16x4*>(x2 + off);
    const float4 bi = reinterpret_cast<const float4*>(b2)[(off >> 2) & 255];
    float4 v;
    v.x = bf2f(c[0]) + bi.x; v.y = bf2f(c[1]) + bi.y;
    v.z = bf2f(c[2]) + bi.z; v.w = bf2f(c[3]) + bi.w;
#pragma unroll
    for (int z = 0; z < 2; z++) {
        const bf16x4 a = *reinterpret_cast<const bf16x4*>(pA + z * zs + off);
        const bf16x4 b = *reinterpret_cast<const bf16x4*>(pB + z * zs + off);
        v.x += bf2f(a[0]) + bf2f(b[0]);
        v.y += bf2f(a[1]) + bf2f(b[1]);
        v.z += bf2f(a[2]) + bf2f(b[2]);
        v.w += bf2f(a[3]) + bf2f(b[3]);
    }
    *reinterpret_cast<float4*>(outp + off) = v;
}

// ---------------- 128x128 GEMM, BK=32, 4 waves, 3-buffer LDS ring (R6-proven)
enum { EPI_QKV = 0, EPI_GELU = 1, EPI_PARTB = 2 };

template <int EPI>
__global__ __launch_bounds__(256, 3) void k_gemm2(
    const bf16_t* __restrict__ A, const bf16_t* __restrict__ BT,
    const float* __restrict__ bias0, const float* __restrict__ bias1,
    const float* __restrict__ bias2,
    bf16_t* __restrict__ outB, bf16_t* __restrict__ outB2,
    bf16_t* __restrict__ outB3,
    int M, int N, int Ksub, int Kstr, long long zstride) {
    int mb, nb;
    tile_coords(gridDim.x, gridDim.y, mb, nb);
    const int mbase = mb * 128;
    const int nbase = nb * 128;

    const bf16_t* Ab = A + (size_t)blockIdx.z * Ksub;
    const bf16_t* Bb = BT + (size_t)blockIdx.z * Ksub;

    const int t = threadIdx.x;
    const int w = t >> 6, l = t & 63;
    const int wr = w >> 1, wc = w & 1;
    const int lrow = l & 15, lg = l >> 4;

    __shared__ alignas(16) bf16_t As[3][128 * 32];
    __shared__ alignas(16) bf16_t Bs[3][128 * 32];

    f32x4 acc[4][4] = {};

    const int sr = t >> 2;
    const int sc = t & 3;
    const int ssw = (sc ^ ((sr >> 1) & 3)) * 8;

    auto stage = [&](int ks, int buf) {
        const int k0 = ks << 5;
#pragma unroll
        for (int c = 0; c < 2; c++)
            async_lds16(Ab + (size_t)(mbase + c * 64 + sr) * Kstr + k0 + ssw,
                        &As[buf][c * 2048 + t * 8]);
#pragma unroll
        for (int c = 0; c < 2; c++)
            async_lds16(Bb + (size_t)(nbase + c * 64 + sr) * Kstr + k0 + ssw,
                        &Bs[buf][c * 2048 + t * 8]);
    };

    stage(0, 0);
    stage(1, 1);
    const int nt = Ksub >> 5;
    int cur = 0;
    for (int tt = 0; tt < nt; tt++) {
        asm volatile("s_waitcnt vmcnt(4)" ::: "memory");
        __builtin_amdgcn_sched_barrier(0);
        __builtin_amdgcn_s_barrier();
        __builtin_amdgcn_sched_barrier(0);
        if (tt + 2 < nt) {
            int nbuf = cur + 2; if (nbuf >= 3) nbuf -= 3;
            stage(tt + 2, nbuf);
        }
        bf16x8 a[4], b[4];
#pragma unroll
        for (int i = 0; i < 4; i++) {
            const int r = wr * 64 + i * 16 + lrow;
            a[i] = *reinterpret_cast<const bf16x8*>(
                &As[cur][r * 32 + ((lg ^ ((r >> 1) & 3)) * 8)]);
        }
#pragma unroll
        for (int j = 0; j < 4; j++) {
            const int r = wc * 64 + j * 16 + lrow;
            b[j] = *reinterpret_cast<const bf16x8*>(
                &Bs[cur][r * 32 + ((lg ^ ((r >> 1) & 3)) * 8)]);
        }
        __builtin_amdgcn_s_setprio(1);
#pragma unroll
        for (int i = 0; i < 4; i++)
#pragma unroll
            for (int j = 0; j < 4; j++)
                acc[i][j] = __builtin_amdgcn_mfma_f32_16x16x32_bf16(a[i], b[j], acc[i][j], 0, 0, 0);
        __builtin_amdgcn_s_setprio(0);
        cur = cur + 1; if (cur >= 3) cur = 0;
    }

#pragma unroll
    for (int i = 0; i < 4; i++) {
#pragma unroll
        for (int j = 0; j < 4; j++) {
            const int col = nbase + wc * 64 + j * 16 + lrow;
            float bj = 0.f;
            int kind = 0, cc = col;
            if constexpr (EPI == EPI_QKV) {
                kind = col >> 10; cc = col & 1023;
                bj = (kind == 0 ? bias0 : kind == 1 ? bias1 : bias2)[cc];
            } else if constexpr (EPI == EPI_GELU) {
                bj = bias0[col];
            }
#pragma unroll
            for (int r = 0; r < 4; r++) {
                const int row = mbase + wr * 64 + i * 16 + lg * 4 + r;
                const float v = acc[i][j][r] + bj;
                if constexpr (EPI == EPI_QKV) {
                    const int bidx = row >> 10, ns = row & 1023;
                    const int hh = cc >> 6, ch = cc & 63;
                    const int bhh = bidx * 16 + hh;
                    if (kind == 0)
                        outB[((size_t)bhh * 1024 + ns) * 64 + ch] = (bf16_t)(v * 0.125f);
                    else if (kind == 1)
                        outB2[((size_t)bhh * 1024 + ns) * 64 + ch] = (bf16_t)v;
                    else
                        outB3[((size_t)bhh * 64 + ch) * 1024 + ns] = (bf16_t)v;
                } else if constexpr (EPI == EPI_GELU) {
                    const float ge = 0.5f * v * (1.0f + erff(v * 0.70710678118654752f));
                    outB[(size_t)row * N + col] = (bf16_t)ge;
                } else {
                    bf16_t* po = (blockIdx.z < 2 ? outB : outB2) +
                                 (size_t)(blockIdx.z & 1) * zstride;
                    po[(size_t)row * N + col] = (bf16_t)v;
                }
            }
        }
    }
}

// ---------------- 256x256 GEMM, BK=64, 8 waves, 2-phase with STAGGERED staging
// (R11/R14 version — best measured: 59.5us GELU; setprio kept per R13 A/B.)
template <int EPI>
__global__ __launch_bounds__(512, 2) void k_gemm256(
    const bf16_t* __restrict__ A, const bf16_t* __restrict__ BT,
    const float* __restrict__ bias0,
    bf16_t* __restrict__ outB, bf16_t* __restrict__ outB2,
    int M, int N, int Ksub, int Kstr, long long zstride) {
    int mb, nb;
    tile_coords(gridDim.x, gridDim.y, mb, nb);
    const int mbase = mb * 256;
    const int nbase = nb * 256;

    const bf16_t* Ab = A + (size_t)blockIdx.z * Ksub;
    const bf16_t* Bb = BT + (size_t)blockIdx.z * Ksub;

    const int t = threadIdx.x;
    const int w = t >> 6, l = t & 63;
    const int wr = w >> 2, wc = w & 3;
    const int lrow = l & 15, lg = l >> 4;

    __shared__ alignas(16) bf16_t As[2][256 * 64];
    __shared__ alignas(16) bf16_t Bs[2][256 * 64];

    f32x4 acc[8][4] = {};

    const int sr = t >> 3;
    const int ssw = ((t & 7) ^ (sr & 7)) * 8;

    const bf16_t* pa = Ab + (size_t)(mbase + sr) * Kstr + ssw;
    const bf16_t* pb = Bb + (size_t)(nbase + sr) * Kstr + ssw;

    auto stageA = [&](int kt, int buf, int half) {
        const int k0 = kt << 6;
#pragma unroll
        for (int i = 0; i < 2; i++)
            async_lds16(pa + (size_t)((half * 2 + i) * 64) * Kstr + k0,
                        &As[buf][(half * 2 + i) * 4096 + t * 8]);
    };
    auto stageB = [&](int kt, int buf, int half) {
        const int k0 = kt << 6;
#pragma unroll
        for (int i = 0; i < 2; i++)
            async_lds16(pb + (size_t)((half * 2 + i) * 64) * Kstr + k0,
                        &Bs[buf][(half * 2 + i) * 4096 + t * 8]);
    };

    stageA(0, 0, 0); stageA(0, 0, 1); stageB(0, 0, 0); stageB(0, 0, 1);
    __syncthreads();
    const int nt = Ksub >> 6;
    for (int kt = 0; kt < nt; kt++) {
        const int cur = kt & 1;
        const bool pf = (kt + 1) < nt;
        if (pf) stageA(kt + 1, cur ^ 1, 0);         // group 1
        bf16x8 bfr[4][2];
#pragma unroll
        for (int fj = 0; fj < 4; fj++) {
            const int rb = wc * 64 + fj * 16 + lrow;
#pragma unroll
            for (int ks = 0; ks < 2; ks++)
                bfr[fj][ks] = *reinterpret_cast<const bf16x8*>(
                    &Bs[cur][rb * 64 + (((ks * 4 + lg) ^ (rb & 7)) * 8)]);
        }
        if (pf) stageA(kt + 1, cur ^ 1, 1);         // group 2
        // h = 0
        {
            bf16x8 afr[4][2];
#pragma unroll
            for (int fi = 0; fi < 4; fi++) {
                const int ra = wr * 64 + fi * 16 + lrow;
#pragma unroll
                for (int ks = 0; ks < 2; ks++)
                    afr[fi][ks] = *reinterpret_cast<const bf16x8*>(
                        &As[cur][ra * 64 + (((ks * 4 + lg) ^ (ra & 7)) * 8)]);
            }
            __builtin_amdgcn_s_setprio(1);
#pragma unroll
            for (int fi = 0; fi < 4; fi++)
#pragma unroll
                for (int fj = 0; fj < 4; fj++)
#pragma unroll
                    for (int ks = 0; ks < 2; ks++)
                        acc[fi][fj] = __builtin_amdgcn_mfma_f32_16x16x32_bf16(
                            afr[fi][ks], bfr[fj][ks], acc[fi][fj], 0, 0, 0);
            __builtin_amdgcn_s_setprio(0);
        }
        if (pf) stageB(kt + 1, cur ^ 1, 0);         // group 3
        // h = 1
        {
            bf16x8 afr[4][2];
#pragma unroll
            for (int fi = 0; fi < 4; fi++) {
                const int ra = 128 + wr * 64 + fi * 16 + lrow;
#pragma unroll
                for (int ks = 0; ks < 2; ks++)
                    afr[fi][ks] = *reinterpret_cast<const bf16x8*>(
                        &As[cur][ra * 64 + (((ks * 4 + lg) ^ (ra & 7)) * 8)]);
            }
            if (pf) stageB(kt + 1, cur ^ 1, 1);     // group 4
            __builtin_amdgcn_s_setprio(1);
#pragma unroll
            for (int fi = 0; fi < 4; fi++)
#pragma unroll
                for (int fj = 0; fj < 4; fj++)
#pragma unroll
                    for (int ks = 0; ks < 2; ks++)
                        acc[4 + fi][fj] = __builtin_amdgcn_mfma_f32_16x16x32_bf16(
                            afr[fi][ks], bfr[fj][ks], acc[4 + fi][fj], 0, 0, 0);
            __builtin_amdgcn_s_setprio(0);
        }
        __syncthreads();   // vmcnt(0)+barrier: prefetch landed, swap safe
    }

#pragma unroll
    for (int h = 0; h < 2; h++) {
#pragma unroll
        for (int fi = 0; fi < 4; fi++) {
#pragma unroll
            for (int fj = 0; fj < 4; fj++) {
                const int col = nbase + wc * 64 + fj * 16 + lrow;
                float bj = 0.f;
                if constexpr (EPI == EPI_GELU) bj = bias0[col];
#pragma unroll
                for (int r = 0; r < 4; r++) {
                    const int row = mbase + h * 128 + wr * 64 + fi * 16 + lg * 4 + r;
                    const float v = acc[h * 4 + fi][fj][r] + bj;
                    if constexpr (EPI == EPI_GELU) {
                        const float ge = 0.5f * v * (1.0f + erff(v * 0.70710678118654752f));
                        outB[(size_t)row * N + col] = (bf16_t)ge;
                    } else {
                        bf16_t* po = (blockIdx.z < 2 ? outB : outB2) +
                                     (size_t)(blockIdx.z & 1) * zstride;
                        po[(size_t)row * N + col] = (bf16_t)v;
                    }
                }
            }
        }
    }
}

// ---------------- flash attention (blocks 0-1023) + W1/W2/Wo transposes
// (blocks 1024-10239, reusing attn LDS; outputs consumed >=1 dispatch later)
__global__ __launch_bounds__(256, 6) void k_attn(
    const bf16_t* __restrict__ q, const bf16_t* __restrict__ kk,
    const bf16_t* __restrict__ vt, const unsigned char* __restrict__ pad,
    bf16_t* __restrict__ o,
    const float* __restrict__ W1, const float* __restrict__ W2,
    const float* __restrict__ Wo,
    bf16_t* __restrict__ W1T, bf16_t* __restrict__ W2T,
    bf16_t* __restrict__ WoT) {
    const int t = threadIdx.x;

    __shared__ alignas(16) bf16_t Ks[2][64 * 64];
    __shared__ alignas(16) bf16_t Vs[2][64 * 64];
    __shared__ alignas(16) bf16_t Ps[4][16 * 64];
    __shared__ unsigned char padRow[1024];

    if (blockIdx.x >= 1024) {   // transpose blocks (fill idle CU capacity)
        const int b = blockIdx.x - 1024;
        const float* src; bf16_t* dst; int R, C, gxx, tile;
        if (b < 4096) { tile = b; gxx = 128; R = 1024; C = 4096; src = W1; dst = W1T; }
        else if (b < 8192) { tile = b - 4096; gxx = 32; R = 4096; C = 1024; src = W2; dst = W2T; }
        else { tile = b - 8192; gxx = 32; R = 1024; C = 1024; src = Wo; dst = WoT; }
        const int r0 = (tile / gxx) << 5, c0 = (tile % gxx) << 5;
        float* tl = reinterpret_cast<float*>(Ks);   // 4.2KB scratch in attn LDS
        const int tx = t & 31, ty = t >> 5;
#pragma unroll
        for (int i = 0; i < 32; i += 8)
            tl[(ty + i) * 33 + tx] = src[(size_t)(r0 + ty + i) * C + c0 + tx];
        __syncthreads();
#pragma unroll
        for (int i = 0; i < 32; i += 8)
            dst[(size_t)(c0 + ty + i) * R + r0 + tx] = (bf16_t)tl[tx * 33 + ty + i];
        return;
    }

    const int qt = 15 - (blockIdx.x >> 6);   // LPT: longest first
    const int bh = blockIdx.x & 63;
    const int bb = bh >> 4, hh = bh & 15;
    const int w = t >> 6, l = t & 63;
    const int lrow = l & 15, lg = l >> 4;
    const int qbase = qt * 64;

    const size_t bh_off = (size_t)bh * 1024 * 64;
    *reinterpret_cast<uchar4*>(&padRow[t * 4]) =
        *reinterpret_cast<const uchar4*>(&pad[bb * 1024 + t * 4]);

    const int qrow = qbase + w * 16 + lrow;
    bf16x8 qf[2];
#pragma unroll
    for (int ks = 0; ks < 2; ks++)
        qf[ks] = *reinterpret_cast<const bf16x8*>(q + bh_off + (size_t)qrow * 64 + ks * 32 + lg * 8);

    f32x4 oacc[4] = {};
    float mrow[4] = {-1e30f, -1e30f, -1e30f, -1e30f};
    float lsum[4] = {0.f, 0.f, 0.f, 0.f};

    const int sr = t >> 3;
    const int ssw = ((t & 7) ^ (sr & 7)) * 8;

    auto stage = [&](int kb, int buf) {
        const bf16_t* kp = kk + bh_off + (size_t)kb * 64;
        async_lds16(kp + (size_t)sr * 64 + ssw, &Ks[buf][t * 8]);
        async_lds16(kp + (size_t)(32 + sr) * 64 + ssw, &Ks[buf][2048 + t * 8]);
        const bf16_t* vp = vt + bh_off + kb;
        async_lds16(vp + (size_t)sr * 1024 + ssw, &Vs[buf][t * 8]);
        async_lds16(vp + (size_t)(32 + sr) * 1024 + ssw, &Vs[buf][2048 + t * 8]);
    };

    stage(0, 0);
    asm volatile("s_waitcnt lgkmcnt(0)" ::: "memory");
    const int nkb = qt + 1;
    for (int ib = 0; ib < nkb; ib++) {
        const int cur = ib & 1;
        const int kb = ib * 64;
        asm volatile("s_waitcnt vmcnt(0)" ::: "memory");
        __builtin_amdgcn_sched_barrier(0);
        __builtin_amdgcn_s_barrier();
        __builtin_amdgcn_sched_barrier(0);
        if (ib + 1 < nkb) stage(kb + 64, cur ^ 1);

        f32x4 s[4] = {};
#pragma unroll
        for (int ks = 0; ks < 2; ks++) {
#pragma unroll
            for (int jt = 0; jt < 4; jt++) {
                const int kr = jt * 16 + lrow;
                bf16x8 bfr = *reinterpret_cast<const bf16x8*>(
                    &Ks[cur][kr * 64 + (((ks * 4 + lg) ^ (kr & 7)) * 8)]);
                s[jt] = __builtin_amdgcn_mfma_f32_16x16x32_bf16(qf[ks], bfr, s[jt], 0, 0, 0);
            }
        }
#pragma unroll
        for (int jt = 0; jt < 4; jt++) {
            const int kvg = kb + jt * 16 + lrow;
            const bool padm = padRow[kvg] != 0;
#pragma unroll
            for (int r = 0; r < 4; r++) {
                const int qg = qbase + w * 16 + lg * 4 + r;
                if (kvg > qg || padm) s[jt][r] = -1e30f;
            }
        }
        float mx[4];
#pragma unroll
        for (int r = 0; r < 4; r++) {
            float m0 = fmaxf(fmaxf(s[0][r], s[1][r]), fmaxf(s[2][r], s[3][r]));
#pragma unroll
            for (int mk = 8; mk >= 1; mk >>= 1) m0 = fmaxf(m0, __shfl_xor(m0, mk));
            mx[r] = m0;
        }
        const bool need = (mx[0] > mrow[0] + 8.f) || (mx[1] > mrow[1] + 8.f) ||
                          (mx[2] > mrow[2] + 8.f) || (mx[3] > mrow[3] + 8.f);
        if (__any(need)) {
#pragma unroll
            for (int r = 0; r < 4; r++) {
                const float mn = fmaxf(mrow[r], mx[r]);
                const float al = __expf(mrow[r] - mn);
                mrow[r] = mn;
                lsum[r] *= al;
#pragma unroll
                for (int ct = 0; ct < 4; ct++) oacc[ct][r] *= al;
            }
        }
#pragma unroll
        for (int jt = 0; jt < 4; jt++)
#pragma unroll
            for (int r = 0; r < 4; r++)
                s[jt][r] = __expf(s[jt][r] - mrow[r]);
#pragma unroll
        for (int r = 0; r < 4; r++) {
            float sm = s[0][r] + s[1][r] + s[2][r] + s[3][r];
#pragma unroll
            for (int mk = 8; mk >= 1; mk >>= 1) sm += __shfl_xor(sm, mk);
            lsum[r] += sm;
        }
#pragma unroll
        for (int jt = 0; jt < 4; jt++)
#pragma unroll
            for (int r = 0; r < 4; r++) {
                const int prow = lg * 4 + r;
                const int kvc = jt * 16 + lrow;
                Ps[w][prow * 64 + (((kvc >> 3) ^ (prow & 7)) * 8) + (kvc & 7)] = (bf16_t)s[jt][r];
            }
#pragma unroll
        for (int ks = 0; ks < 2; ks++) {
            bf16x8 pa = *reinterpret_cast<const bf16x8*>(
                &Ps[w][lrow * 64 + (((ks * 4 + lg) ^ (lrow & 7)) * 8)]);
#pragma unroll
            for (int ct = 0; ct < 4; ct++) {
                const int vr = ct * 16 + lrow;
                bf16x8 vb = *reinterpret_cast<const bf16x8*>(
                    &Vs[cur][vr * 64 + (((ks * 4 + lg) ^ (vr & 7)) * 8)]);
                oacc[ct] = __builtin_amdgcn_mfma_f32_16x16x32_bf16(pa, vb, oacc[ct], 0, 0, 0);
            }
        }
    }
#pragma unroll
    for (int ct = 0; ct < 4; ct++) {
#pragma unroll
        for (int r = 0; r < 4; r++) {
            const int qg = qbase + w * 16 + lg * 4 + r;
            const float val = oacc[ct][r] / lsum[r];
            o[((size_t)bb * 1024 + qg) * 1024 + hh * 64 + ct * 16 + lrow] = (bf16_t)val;
        }
    }
}

extern "C" void kernel_launch(void* const* d_in, const int* in_sizes, int n_in,
                              void* d_out, int out_size, void* d_ws, size_t ws_size,
                              hipStream_t stream) {
    const float* x    = (const float*)d_in[0];
    const float* ln1g = (const float*)d_in[1];
    const float* ln1b = (const float*)d_in[2];
    const float* Wq   = (const float*)d_in[3];
    const float* bq   = (const float*)d_in[4];
    const float* Wk   = (const float*)d_in[5];
    const float* bk   = (const float*)d_in[6];
    const float* Wv   = (const float*)d_in[7];
    const float* bv   = (const float*)d_in[8];
    const float* Wo   = (const float*)d_in[9];
    const float* bo   = (const float*)d_in[10];
    const float* ln2g = (const float*)d_in[11];
    const float* ln2b = (const float*)d_in[12];
    const float* W1   = (const float*)d_in[13];
    const float* b1   = (const float*)d_in[14];
    const float* W2   = (const float*)d_in[15];
    const float* b2   = (const float*)d_in[16];
    const unsigned char* pad = (const unsigned char*)d_in[17];

    char* ws = (char*)d_ws;
    const size_t MB = 1024 * 1024;
    bf16_t* WqkvT = (bf16_t*)(ws + 0 * MB);   // 6MB  [dead after QKV]
    bf16_t* WoT = (bf16_t*)(ws + 6 * MB);     // 2MB  [dead after O-proj]
    bf16_t* W1T = (bf16_t*)(ws + 8 * MB);     // 8MB  [dead after GELU]
    bf16_t* W2T = (bf16_t*)(ws + 16 * MB);    // 8MB  [dead after W2]
    bf16_t* h   = (bf16_t*)(ws + 24 * MB);    // 8MB  [dead after QKV]
    bf16_t* qb  = (bf16_t*)(ws + 32 * MB);    // 8MB  [dead after attn]
    bf16_t* kb  = (bf16_t*)(ws + 40 * MB);    // 8MB  [dead after attn]
    bf16_t* vb  = (bf16_t*)(ws + 48 * MB);    // 8MB  [dead after attn] (V^T)
    bf16_t* ob  = (bf16_t*)(ws + 56 * MB);    // 8MB  [dead after O-proj]
    bf16_t* ppO = (bf16_t*)(ws + 24 * MB);    // 4x8MB @24-56 [O-proj partials]
    bf16_t* m2  = (bf16_t*)(ws + 56 * MB);    // 8MB  @56-64 [dead after GELU]
    bf16_t* x2  = (bf16_t*)(ws + 64 * MB);    // 8MB  @64-72 [alive to end, bf16]
    bf16_t* hid = (bf16_t*)(ws + 24 * MB);    // 32MB @24-56 [dead after W2]
    bf16_t* pW01 = (bf16_t*)(ws + 0 * MB);    // 2x8MB @0-16
    bf16_t* pW23 = (bf16_t*)(ws + 80 * MB);   // 2x8MB @80-96

    const long long ZS = 4ll * 1024 * 1024;

    const dim3 blk(256);
    const dim3 blk8(512);
    // Wq/Wk/Wv transposes + LN1 (Wo/W1/W2 transposes moved into attn grid)
    k_prep<<<7168, blk, 0, stream>>>(
        Wq, Wk, Wv,
        WqkvT, WqkvT + 1024 * 1024, WqkvT + 2048 * 1024,
        x, ln1g, ln1b, h);
    // fused QKV projection: 768 blocks (3/CU), ring + supertile
    k_gemm2<EPI_QKV><<<dim3(24, 32), blk, 0, stream>>>(
        h, WqkvT, bq, bk, bv, qb, kb, vb, 4096, 3072, 1024, 1024, 0);
    // attention (1024 blocks, LPT) + W1/W2/Wo transposes (9216 filler blocks)
    k_attn<<<10240, blk, 0, stream>>>(qb, kb, vb, pad, ob, W1, W2, Wo,
                                      W1T, W2T, WoT);
    // O-proj split-K x4: 1024 blocks, Ksub=256; bf16 partials @24-56
    k_gemm2<EPI_PARTB><<<dim3(8, 32, 4), blk, 0, stream>>>(
        ob, WoT, nullptr, nullptr, nullptr, ppO, ppO + 2 * ZS, nullptr,
        4096, 1024, 256, 1024, ZS);
    // reduce 4 partials + bias + residual + LN2 -> x2 (bf16), m2 (bf16)
    k_reduce_ln4<<<4096, blk, 0, stream>>>(ppO, bo, x, ln2g, ln2b, x2, m2, ZS);
    // MLP up + GELU: 256-sq staggered 2-phase + supertile, 256 blocks
    k_gemm256<EPI_GELU><<<dim3(16, 16), blk8, 0, stream>>>(
        m2, W1T, b1, hid, nullptr, 4096, 4096, 1024, 1024, 0);
    // MLP down split-K x4: 256-sq staggered 2-phase + supertile, 256 blocks
    k_gemm256<EPI_PARTB><<<dim3(4, 16, 4), blk8, 0, stream>>>(
        hid, W2T, nullptr, pW01, pW23, 4096, 1024, 1024, 4096, ZS);
    // final reduce: d_out = pW01(2) + pW23(2) + b2 + x2
    k_reduce_out4<<<4096, blk, 0, stream>>>(pW01, pW23, b2, x2, (float*)d_out, ZS);
}

// Round 17
// 222.116 us; speedup vs baseline: 1.0037x; 1.0037x over previous
//
#include <hip/hip_runtime.h>
#include <hip/hip_bf16.h>
#include <cmath>

typedef __bf16 bf16_t;
typedef __bf16 bf16x8 __attribute__((ext_vector_type(8)));
typedef __bf16 bf16x4 __attribute__((ext_vector_type(4)));
typedef float f32x4 __attribute__((ext_vector_type(4)));

#define AS1 __attribute__((address_space(1)))
#define AS3 __attribute__((address_space(3)))

__device__ __forceinline__ void async_lds16(const void* g, void* s) {
    __builtin_amdgcn_global_load_lds((const AS1 void*)g, (AS3 void*)s, 16, 0, 0);
}

__device__ __forceinline__ float bf2f(bf16_t v) { return (float)v; }

// XCD chunking + 4x4 supertile decode (kept: -33% FETCH)
__device__ __forceinline__ void tile_coords(int gx, int gy, int& mb, int& nb) {
    const int nwg = gx * gy;
    int lin = blockIdx.y * gx + blockIdx.x;
    if ((nwg & 7) == 0) lin = (lin & 7) * (nwg >> 3) + (lin >> 3);
    if ((gx & 3) == 0 && (gy & 3) == 0) {
        const int st = lin >> 4, pos = lin & 15;
        const int stn = gx >> 2;
        mb = (st / stn) * 4 + (pos >> 2);
        nb = (st % stn) * 4 + (pos & 3);
    } else {
        mb = lin / gx; nb = lin % gx;
    }
}

// ---------------- small weight transposes + LN1 (8192 blocks)
// b<4096: Wq/Wk/Wv/Wo (1024x1024); else LN1 row (b-4096)
__global__ __launch_bounds__(256) void k_prep(
    const float* __restrict__ s0, const float* __restrict__ s1,
    const float* __restrict__ s2, const float* __restrict__ s3,
    bf16_t* __restrict__ d0, bf16_t* __restrict__ d1, bf16_t* __restrict__ d2,
    bf16_t* __restrict__ d3,
    const float* __restrict__ x, const float* __restrict__ g,
    const float* __restrict__ bln, bf16_t* __restrict__ hout) {
    const int b = blockIdx.x;
    const int t = threadIdx.x;
    if (b >= 4096) {  // LN1 row
        const int row = b - 4096;
        const float4 xv = reinterpret_cast<const float4*>(x + (size_t)row * 1024)[t];
        float s = xv.x + xv.y + xv.z + xv.w;
        float s2 = xv.x * xv.x + xv.y * xv.y + xv.z * xv.z + xv.w * xv.w;
#pragma unroll
        for (int mk = 32; mk >= 1; mk >>= 1) {
            s += __shfl_xor(s, mk);
            s2 += __shfl_xor(s2, mk);
        }
        __shared__ float red[8];
        const int w = t >> 6, l = t & 63;
        if (l == 0) { red[w] = s; red[4 + w] = s2; }
        __syncthreads();
        s = red[0] + red[1] + red[2] + red[3];
        s2 = red[4] + red[5] + red[6] + red[7];
        const float mu = s * (1.0f / 1024.0f);
        const float var = s2 * (1.0f / 1024.0f) - mu * mu;
        const float rs = rsqrtf(var + 1e-5f);
        const float4 gv = reinterpret_cast<const float4*>(g)[t];
        const float4 bv = reinterpret_cast<const float4*>(bln)[t];
        bf16x4 o4;
        o4[0] = (bf16_t)((xv.x - mu) * rs * gv.x + bv.x);
        o4[1] = (bf16_t)((xv.y - mu) * rs * gv.y + bv.y);
        o4[2] = (bf16_t)((xv.z - mu) * rs * gv.z + bv.z);
        o4[3] = (bf16_t)((xv.w - mu) * rs * gv.w + bv.w);
        *reinterpret_cast<bf16x4*>(hout + (size_t)row * 1024 + t * 4) = o4;
        return;
    }
    const int m = b >> 10;
    const int tile = b & 1023;
    const float* src = m == 0 ? s0 : m == 1 ? s1 : m == 2 ? s2 : s3;
    bf16_t* dst = m == 0 ? d0 : m == 1 ? d1 : m == 2 ? d2 : d3;
    const int r0 = (tile >> 5) << 5, c0 = (tile & 31) << 5;
    __shared__ float tl[32][33];
    const int tx = t & 31, ty = t >> 5;
#pragma unroll
    for (int i = 0; i < 32; i += 8)
        tl[ty + i][tx] = src[(size_t)(r0 + ty + i) * 1024 + c0 + tx];
    __syncthreads();
#pragma unroll
    for (int i = 0; i < 32; i += 8)
        dst[(size_t)(c0 + ty + i) * 1024 + r0 + tx] = (bf16_t)tl[tx][ty + i];
}

// ---------------- 4x bf16 partial reduce + bias + residual + fused LN
__global__ __launch_bounds__(256) void k_reduce_ln4(
    const bf16_t* __restrict__ pp,
    const float* __restrict__ bo, const float* __restrict__ x,
    const float* __restrict__ g, const float* __restrict__ b,
    bf16_t* __restrict__ x2, bf16_t* __restrict__ m2, long long zs) {
    const int row = blockIdx.x;
    const int t = threadIdx.x;
    const size_t off = (size_t)row * 1024 + t * 4;
    const float4 bb = reinterpret_cast<const float4*>(bo)[t];
    const float4 xv = *reinterpret_cast<const float4*>(x + off);
    float4 v;
    v.x = bb.x + xv.x; v.y = bb.y + xv.y; v.z = bb.z + xv.z; v.w = bb.w + xv.w;
#pragma unroll
    for (int z = 0; z < 4; z++) {
        const bf16x4 p = *reinterpret_cast<const bf16x4*>(pp + z * zs + off);
        v.x += bf2f(p[0]); v.y += bf2f(p[1]); v.z += bf2f(p[2]); v.w += bf2f(p[3]);
    }
    bf16x4 xo;
    xo[0] = (bf16_t)v.x; xo[1] = (bf16_t)v.y; xo[2] = (bf16_t)v.z; xo[3] = (bf16_t)v.w;
    *reinterpret_cast<bf16x4*>(x2 + off) = xo;
    float s = v.x + v.y + v.z + v.w;
    float s2 = v.x * v.x + v.y * v.y + v.z * v.z + v.w * v.w;
#pragma unroll
    for (int mk = 32; mk >= 1; mk >>= 1) {
        s += __shfl_xor(s, mk);
        s2 += __shfl_xor(s2, mk);
    }
    __shared__ float red[8];
    const int w = t >> 6, l = t & 63;
    if (l == 0) { red[w] = s; red[4 + w] = s2; }
    __syncthreads();
    s = red[0] + red[1] + red[2] + red[3];
    s2 = red[4] + red[5] + red[6] + red[7];
    const float mu = s * (1.0f / 1024.0f);
    const float var = s2 * (1.0f / 1024.0f) - mu * mu;
    const float rs = rsqrtf(var + 1e-5f);
    const float4 gv = reinterpret_cast<const float4*>(g)[t];
    const float4 bv = reinterpret_cast<const float4*>(b)[t];
    bf16x4 o4;
    o4[0] = (bf16_t)((v.x - mu) * rs * gv.x + bv.x);
    o4[1] = (bf16_t)((v.y - mu) * rs * gv.y + bv.y);
    o4[2] = (bf16_t)((v.z - mu) * rs * gv.z + bv.z);
    o4[3] = (bf16_t)((v.w - mu) * rs * gv.w + bv.w);
    *reinterpret_cast<bf16x4*>(m2 + off) = o4;
}

// ---------------- final reduce: d_out = pA(2) + pB(2) + b2 + x2(bf16)
__global__ __launch_bounds__(256) void k_reduce_out4(
    const bf16_t* __restrict__ pA, const bf16_t* __restrict__ pB,
    const float* __restrict__ b2, const bf16_t* __restrict__ x2,
    float* __restrict__ outp, long long zs) {
    const size_t off = ((size_t)blockIdx.x * 256 + threadIdx.x) * 4;
    const bf16x4 c = *reinterpret_cast<const bf16x4*>(x2 + off);
    const float4 bi = reinterpret_cast<const float4*>(b2)[(off >> 2) & 255];
    float4 v;
    v.x = bf2f(c[0]) + bi.x; v.y = bf2f(c[1]) + bi.y;
    v.z = bf2f(c[2]) + bi.z; v.w = bf2f(c[3]) + bi.w;
#pragma unroll
    for (int z = 0; z < 2; z++) {
        const bf16x4 a = *reinterpret_cast<const bf16x4*>(pA + z * zs + off);
        const bf16x4 b = *reinterpret_cast<const bf16x4*>(pB + z * zs + off);
        v.x += bf2f(a[0]) + bf2f(b[0]);
        v.y += bf2f(a[1]) + bf2f(b[1]);
        v.z += bf2f(a[2]) + bf2f(b[2]);
        v.w += bf2f(a[3]) + bf2f(b[3]);
    }
    *reinterpret_cast<float4*>(outp + off) = v;
}

// ---------------- 128x128 GEMM, BK=32, 4 waves, 3-buffer LDS ring (R6-proven)
enum { EPI_QKV = 0, EPI_GELU = 1, EPI_PARTB = 2 };

template <int EPI>
__global__ __launch_bounds__(256, 3) void k_gemm2(
    const bf16_t* __restrict__ A, const bf16_t* __restrict__ BT,
    const float* __restrict__ bias0, const float* __restrict__ bias1,
    const float* __restrict__ bias2,
    bf16_t* __restrict__ outB, bf16_t* __restrict__ outB2,
    bf16_t* __restrict__ outB3,
    int M, int N, int Ksub, int Kstr, long long zstride) {
    int mb, nb;
    tile_coords(gridDim.x, gridDim.y, mb, nb);
    const int mbase = mb * 128;
    const int nbase = nb * 128;

    const bf16_t* Ab = A + (size_t)blockIdx.z * Ksub;
    const bf16_t* Bb = BT + (size_t)blockIdx.z * Ksub;

    const int t = threadIdx.x;
    const int w = t >> 6, l = t & 63;
    const int wr = w >> 1, wc = w & 1;
    const int lrow = l & 15, lg = l >> 4;

    __shared__ alignas(16) bf16_t As[3][128 * 32];
    __shared__ alignas(16) bf16_t Bs[3][128 * 32];

    f32x4 acc[4][4] = {};

    const int sr = t >> 2;
    const int sc = t & 3;
    const int ssw = (sc ^ ((sr >> 1) & 3)) * 8;

    auto stage = [&](int ks, int buf) {
        const int k0 = ks << 5;
#pragma unroll
        for (int c = 0; c < 2; c++)
            async_lds16(Ab + (size_t)(mbase + c * 64 + sr) * Kstr + k0 + ssw,
                        &As[buf][c * 2048 + t * 8]);
#pragma unroll
        for (int c = 0; c < 2; c++)
            async_lds16(Bb + (size_t)(nbase + c * 64 + sr) * Kstr + k0 + ssw,
                        &Bs[buf][c * 2048 + t * 8]);
    };

    stage(0, 0);
    stage(1, 1);
    const int nt = Ksub >> 5;
    int cur = 0;
    for (int tt = 0; tt < nt; tt++) {
        asm volatile("s_waitcnt vmcnt(4)" ::: "memory");
        __builtin_amdgcn_sched_barrier(0);
        __builtin_amdgcn_s_barrier();
        __builtin_amdgcn_sched_barrier(0);
        if (tt + 2 < nt) {
            int nbuf = cur + 2; if (nbuf >= 3) nbuf -= 3;
            stage(tt + 2, nbuf);
        }
        bf16x8 a[4], b[4];
#pragma unroll
        for (int i = 0; i < 4; i++) {
            const int r = wr * 64 + i * 16 + lrow;
            a[i] = *reinterpret_cast<const bf16x8*>(
                &As[cur][r * 32 + ((lg ^ ((r >> 1) & 3)) * 8)]);
        }
#pragma unroll
        for (int j = 0; j < 4; j++) {
            const int r = wc * 64 + j * 16 + lrow;
            b[j] = *reinterpret_cast<const bf16x8*>(
                &Bs[cur][r * 32 + ((lg ^ ((r >> 1) & 3)) * 8)]);
        }
        __builtin_amdgcn_s_setprio(1);
#pragma unroll
        for (int i = 0; i < 4; i++)
#pragma unroll
            for (int j = 0; j < 4; j++)
                acc[i][j] = __builtin_amdgcn_mfma_f32_16x16x32_bf16(a[i], b[j], acc[i][j], 0, 0, 0);
        __builtin_amdgcn_s_setprio(0);
        cur = cur + 1; if (cur >= 3) cur = 0;
    }

#pragma unroll
    for (int i = 0; i < 4; i++) {
#pragma unroll
        for (int j = 0; j < 4; j++) {
            const int col = nbase + wc * 64 + j * 16 + lrow;
            float bj = 0.f;
            int kind = 0, cc = col;
            if constexpr (EPI == EPI_QKV) {
                kind = col >> 10; cc = col & 1023;
                bj = (kind == 0 ? bias0 : kind == 1 ? bias1 : bias2)[cc];
            } else if constexpr (EPI == EPI_GELU) {
                bj = bias0[col];
            }
#pragma unroll
            for (int r = 0; r < 4; r++) {
                const int row = mbase + wr * 64 + i * 16 + lg * 4 + r;
                const float v = acc[i][j][r] + bj;
                if constexpr (EPI == EPI_QKV) {
                    const int bidx = row >> 10, ns = row & 1023;
                    const int hh = cc >> 6, ch = cc & 63;
                    const int bhh = bidx * 16 + hh;
                    if (kind == 0)
                        outB[((size_t)bhh * 1024 + ns) * 64 + ch] = (bf16_t)(v * 0.125f);
                    else if (kind == 1)
                        outB2[((size_t)bhh * 1024 + ns) * 64 + ch] = (bf16_t)v;
                    else
                        outB3[((size_t)bhh * 64 + ch) * 1024 + ns] = (bf16_t)v;
                } else if constexpr (EPI == EPI_GELU) {
                    const float ge = 0.5f * v * (1.0f + erff(v * 0.70710678118654752f));
                    outB[(size_t)row * N + col] = (bf16_t)ge;
                } else {
                    bf16_t* po = (blockIdx.z < 2 ? outB : outB2) +
                                 (size_t)(blockIdx.z & 1) * zstride;
                    po[(size_t)row * N + col] = (bf16_t)v;
                }
            }
        }
    }
}

// ---------------- 256x256 GEMM, BK=64, 8 waves, 2-phase with STAGGERED staging
template <int EPI>
__global__ __launch_bounds__(512, 2) void k_gemm256(
    const bf16_t* __restrict__ A, const bf16_t* __restrict__ BT,
    const float* __restrict__ bias0,
    bf16_t* __restrict__ outB, bf16_t* __restrict__ outB2,
    int M, int N, int Ksub, int Kstr, long long zstride) {
    int mb, nb;
    tile_coords(gridDim.x, gridDim.y, mb, nb);
    const int mbase = mb * 256;
    const int nbase = nb * 256;

    const bf16_t* Ab = A + (size_t)blockIdx.z * Ksub;
    const bf16_t* Bb = BT + (size_t)blockIdx.z * Ksub;

    const int t = threadIdx.x;
    const int w = t >> 6, l = t & 63;
    const int wr = w >> 2, wc = w & 3;
    const int lrow = l & 15, lg = l >> 4;

    __shared__ alignas(16) bf16_t As[2][256 * 64];
    __shared__ alignas(16) bf16_t Bs[2][256 * 64];

    f32x4 acc[8][4] = {};

    const int sr = t >> 3;
    const int ssw = ((t & 7) ^ (sr & 7)) * 8;

    const bf16_t* pa = Ab + (size_t)(mbase + sr) * Kstr + ssw;
    const bf16_t* pb = Bb + (size_t)(nbase + sr) * Kstr + ssw;

    auto stageA = [&](int kt, int buf, int half) {
        const int k0 = kt << 6;
#pragma unroll
        for (int i = 0; i < 2; i++)
            async_lds16(pa + (size_t)((half * 2 + i) * 64) * Kstr + k0,
                        &As[buf][(half * 2 + i) * 4096 + t * 8]);
    };
    auto stageB = [&](int kt, int buf, int half) {
        const int k0 = kt << 6;
#pragma unroll
        for (int i = 0; i < 2; i++)
            async_lds16(pb + (size_t)((half * 2 + i) * 64) * Kstr + k0,
                        &Bs[buf][(half * 2 + i) * 4096 + t * 8]);
    };

    stageA(0, 0, 0); stageA(0, 0, 1); stageB(0, 0, 0); stageB(0, 0, 1);
    __syncthreads();
    const int nt = Ksub >> 6;
    for (int kt = 0; kt < nt; kt++) {
        const int cur = kt & 1;
        const bool pf = (kt + 1) < nt;
        if (pf) stageA(kt + 1, cur ^ 1, 0);         // group 1
        bf16x8 bfr[4][2];
#pragma unroll
        for (int fj = 0; fj < 4; fj++) {
            const int rb = wc * 64 + fj * 16 + lrow;
#pragma unroll
            for (int ks = 0; ks < 2; ks++)
                bfr[fj][ks] = *reinterpret_cast<const bf16x8*>(
                    &Bs[cur][rb * 64 + (((ks * 4 + lg) ^ (rb & 7)) * 8)]);
        }
        if (pf) stageA(kt + 1, cur ^ 1, 1);         // group 2
        // h = 0
        {
            bf16x8 afr[4][2];
#pragma unroll
            for (int fi = 0; fi < 4; fi++) {
                const int ra = wr * 64 + fi * 16 + lrow;
#pragma unroll
                for (int ks = 0; ks < 2; ks++)
                    afr[fi][ks] = *reinterpret_cast<const bf16x8*>(
                        &As[cur][ra * 64 + (((ks * 4 + lg) ^ (ra & 7)) * 8)]);
            }
            __builtin_amdgcn_s_setprio(1);
#pragma unroll
            for (int fi = 0; fi < 4; fi++)
#pragma unroll
                for (int fj = 0; fj < 4; fj++)
#pragma unroll
                    for (int ks = 0; ks < 2; ks++)
                        acc[fi][fj] = __builtin_amdgcn_mfma_f32_16x16x32_bf16(
                            afr[fi][ks], bfr[fj][ks], acc[fi][fj], 0, 0, 0);
            __builtin_amdgcn_s_setprio(0);
        }
        if (pf) stageB(kt + 1, cur ^ 1, 0);         // group 3
        // h = 1
        {
            bf16x8 afr[4][2];
#pragma unroll
            for (int fi = 0; fi < 4; fi++) {
                const int ra = 128 + wr * 64 + fi * 16 + lrow;
#pragma unroll
                for (int ks = 0; ks < 2; ks++)
                    afr[fi][ks] = *reinterpret_cast<const bf16x8*>(
                        &As[cur][ra * 64 + (((ks * 4 + lg) ^ (ra & 7)) * 8)]);
            }
            if (pf) stageB(kt + 1, cur ^ 1, 1);     // group 4
            __builtin_amdgcn_s_setprio(1);
#pragma unroll
            for (int fi = 0; fi < 4; fi++)
#pragma unroll
                for (int fj = 0; fj < 4; fj++)
#pragma unroll
                    for (int ks = 0; ks < 2; ks++)
                        acc[4 + fi][fj] = __builtin_amdgcn_mfma_f32_16x16x32_bf16(
                            afr[fi][ks], bfr[fj][ks], acc[4 + fi][fj], 0, 0, 0);
            __builtin_amdgcn_s_setprio(0);
        }
        __syncthreads();   // vmcnt(0)+barrier: prefetch landed, swap safe
    }

#pragma unroll
    for (int h = 0; h < 2; h++) {
#pragma unroll
        for (int fi = 0; fi < 4; fi++) {
#pragma unroll
            for (int fj = 0; fj < 4; fj++) {
                const int col = nbase + wc * 64 + fj * 16 + lrow;
                float bj = 0.f;
                if constexpr (EPI == EPI_GELU) bj = bias0[col];
#pragma unroll
                for (int r = 0; r < 4; r++) {
                    const int row = mbase + h * 128 + wr * 64 + fi * 16 + lg * 4 + r;
                    const float v = acc[h * 4 + fi][fj][r] + bj;
                    if constexpr (EPI == EPI_GELU) {
                        const float ge = 0.5f * v * (1.0f + erff(v * 0.70710678118654752f));
                        outB[(size_t)row * N + col] = (bf16_t)ge;
                    } else {
                        bf16_t* po = (blockIdx.z < 2 ? outB : outB2) +
                                     (size_t)(blockIdx.z & 1) * zstride;
                        po[(size_t)row * N + col] = (bf16_t)v;
                    }
                }
            }
        }
    }
}

// ---------------- flash attention (blocks 0-1023) + W1/W2 transposes
// (blocks 1024-9215, reusing attn LDS; W1T/W2T consumed 3 dispatches later)
__global__ __launch_bounds__(256, 4) void k_attn(
    const bf16_t* __restrict__ q, const bf16_t* __restrict__ kk,
    const bf16_t* __restrict__ vt, const unsigned char* __restrict__ pad,
    bf16_t* __restrict__ o,
    const float* __restrict__ W1, const float* __restrict__ W2,
    bf16_t* __restrict__ W1T, bf16_t* __restrict__ W2T) {
    const int t = threadIdx.x;

    __shared__ alignas(16) bf16_t Ks[2][64 * 64];
    __shared__ alignas(16) bf16_t Vs[2][64 * 64];
    __shared__ alignas(16) bf16_t Ps[4][16 * 64];
    __shared__ unsigned char padRow[1024];

    if (blockIdx.x >= 1024) {   // transpose blocks (fill idle CU capacity)
        const int b = blockIdx.x - 1024;
        const float* src; bf16_t* dst; int R, C, gxx, tile;
        if (b < 4096) { tile = b; gxx = 128; R = 1024; C = 4096; src = W1; dst = W1T; }
        else { tile = b - 4096; gxx = 32; R = 4096; C = 1024; src = W2; dst = W2T; }
        const int r0 = (tile / gxx) << 5, c0 = (tile % gxx) << 5;
        float* tl = reinterpret_cast<float*>(Ks);   // 4.2KB scratch in attn LDS
        const int tx = t & 31, ty = t >> 5;
#pragma unroll
        for (int i = 0; i < 32; i += 8)
            tl[(ty + i) * 33 + tx] = src[(size_t)(r0 + ty + i) * C + c0 + tx];
        __syncthreads();
#pragma unroll
        for (int i = 0; i < 32; i += 8)
            dst[(size_t)(c0 + ty + i) * R + r0 + tx] = (bf16_t)tl[tx * 33 + ty + i];
        return;
    }

    const int qt = 15 - (blockIdx.x >> 6);   // LPT: longest first
    const int bh = blockIdx.x & 63;
    const int bb = bh >> 4, hh = bh & 15;
    const int w = t >> 6, l = t & 63;
    const int lrow = l & 15, lg = l >> 4;
    const int qbase = qt * 64;

    const size_t bh_off = (size_t)bh * 1024 * 64;
    *reinterpret_cast<uchar4*>(&padRow[t * 4]) =
        *reinterpret_cast<const uchar4*>(&pad[bb * 1024 + t * 4]);

    const int qrow = qbase + w * 16 + lrow;
    bf16x8 qf[2];
#pragma unroll
    for (int ks = 0; ks < 2; ks++)
        qf[ks] = *reinterpret_cast<const bf16x8*>(q + bh_off + (size_t)qrow * 64 + ks * 32 + lg * 8);

    f32x4 oacc[4] = {};
    float mrow[4] = {-1e30f, -1e30f, -1e30f, -1e30f};
    float lsum[4] = {0.f, 0.f, 0.f, 0.f};

    const int sr = t >> 3;
    const int ssw = ((t & 7) ^ (sr & 7)) * 8;

    auto stage = [&](int kb, int buf) {
        const bf16_t* kp = kk + bh_off + (size_t)kb * 64;
        async_lds16(kp + (size_t)sr * 64 + ssw, &Ks[buf][t * 8]);
        async_lds16(kp + (size_t)(32 + sr) * 64 + ssw, &Ks[buf][2048 + t * 8]);
        const bf16_t* vp = vt + bh_off + kb;
        async_lds16(vp + (size_t)sr * 1024 + ssw, &Vs[buf][t * 8]);
        async_lds16(vp + (size_t)(32 + sr) * 1024 + ssw, &Vs[buf][2048 + t * 8]);
    };

    stage(0, 0);
    asm volatile("s_waitcnt lgkmcnt(0)" ::: "memory");
    const int nkb = qt + 1;
    for (int ib = 0; ib < nkb; ib++) {
        const int cur = ib & 1;
        const int kb = ib * 64;
        asm volatile("s_waitcnt vmcnt(0)" ::: "memory");
        __builtin_amdgcn_sched_barrier(0);
        __builtin_amdgcn_s_barrier();
        __builtin_amdgcn_sched_barrier(0);
        if (ib + 1 < nkb) stage(kb + 64, cur ^ 1);

        f32x4 s[4] = {};
#pragma unroll
        for (int ks = 0; ks < 2; ks++) {
#pragma unroll
            for (int jt = 0; jt < 4; jt++) {
                const int kr = jt * 16 + lrow;
                bf16x8 bfr = *reinterpret_cast<const bf16x8*>(
                    &Ks[cur][kr * 64 + (((ks * 4 + lg) ^ (kr & 7)) * 8)]);
                s[jt] = __builtin_amdgcn_mfma_f32_16x16x32_bf16(qf[ks], bfr, s[jt], 0, 0, 0);
            }
        }
#pragma unroll
        for (int jt = 0; jt < 4; jt++) {
            const int kvg = kb + jt * 16 + lrow;
            const bool padm = padRow[kvg] != 0;
#pragma unroll
            for (int r = 0; r < 4; r++) {
                const int qg = qbase + w * 16 + lg * 4 + r;
                if (kvg > qg || padm) s[jt][r] = -1e30f;
            }
        }
        float mx[4];
#pragma unroll
        for (int r = 0; r < 4; r++) {
            float m0 = fmaxf(fmaxf(s[0][r], s[1][r]), fmaxf(s[2][r], s[3][r]));
#pragma unroll
            for (int mk = 8; mk >= 1; mk >>= 1) m0 = fmaxf(m0, __shfl_xor(m0, mk));
            mx[r] = m0;
        }
        const bool need = (mx[0] > mrow[0] + 8.f) || (mx[1] > mrow[1] + 8.f) ||
                          (mx[2] > mrow[2] + 8.f) || (mx[3] > mrow[3] + 8.f);
        if (__any(need)) {
#pragma unroll
            for (int r = 0; r < 4; r++) {
                const float mn = fmaxf(mrow[r], mx[r]);
                const float al = __expf(mrow[r] - mn);
                mrow[r] = mn;
                lsum[r] *= al;
#pragma unroll
                for (int ct = 0; ct < 4; ct++) oacc[ct][r] *= al;
            }
        }
#pragma unroll
        for (int jt = 0; jt < 4; jt++)
#pragma unroll
            for (int r = 0; r < 4; r++)
                s[jt][r] = __expf(s[jt][r] - mrow[r]);
#pragma unroll
        for (int r = 0; r < 4; r++) {
            float sm = s[0][r] + s[1][r] + s[2][r] + s[3][r];
#pragma unroll
            for (int mk = 8; mk >= 1; mk >>= 1) sm += __shfl_xor(sm, mk);
            lsum[r] += sm;
        }
#pragma unroll
        for (int jt = 0; jt < 4; jt++)
#pragma unroll
            for (int r = 0; r < 4; r++) {
                const int prow = lg * 4 + r;
                const int kvc = jt * 16 + lrow;
                Ps[w][prow * 64 + (((kvc >> 3) ^ (prow & 7)) * 8) + (kvc & 7)] = (bf16_t)s[jt][r];
            }
#pragma unroll
        for (int ks = 0; ks < 2; ks++) {
            bf16x8 pa = *reinterpret_cast<const bf16x8*>(
                &Ps[w][lrow * 64 + (((ks * 4 + lg) ^ (lrow & 7)) * 8)]);
#pragma unroll
            for (int ct = 0; ct < 4; ct++) {
                const int vr = ct * 16 + lrow;
                bf16x8 vb = *reinterpret_cast<const bf16x8*>(
                    &Vs[cur][vr * 64 + (((ks * 4 + lg) ^ (vr & 7)) * 8)]);
                oacc[ct] = __builtin_amdgcn_mfma_f32_16x16x32_bf16(pa, vb, oacc[ct], 0, 0, 0);
            }
        }
    }
#pragma unroll
    for (int ct = 0; ct < 4; ct++) {
#pragma unroll
        for (int r = 0; r < 4; r++) {
            const int qg = qbase + w * 16 + lg * 4 + r;
            const float val = oacc[ct][r] / lsum[r];
            o[((size_t)bb * 1024 + qg) * 1024 + hh * 64 + ct * 16 + lrow] = (bf16_t)val;
        }
    }
}

extern "C" void kernel_launch(void* const* d_in, const int* in_sizes, int n_in,
                              void* d_out, int out_size, void* d_ws, size_t ws_size,
                              hipStream_t stream) {
    const float* x    = (const float*)d_in[0];
    const float* ln1g = (const float*)d_in[1];
    const float* ln1b = (const float*)d_in[2];
    const float* Wq   = (const float*)d_in[3];
    const float* bq   = (const float*)d_in[4];
    const float* Wk   = (const float*)d_in[5];
    const float* bk   = (const float*)d_in[6];
    const float* Wv   = (const float*)d_in[7];
    const float* bv   = (const float*)d_in[8];
    const float* Wo   = (const float*)d_in[9];
    const float* bo   = (const float*)d_in[10];
    const float* ln2g = (const float*)d_in[11];
    const float* ln2b = (const float*)d_in[12];
    const float* W1   = (const float*)d_in[13];
    const float* b1   = (const float*)d_in[14];
    const float* W2   = (const float*)d_in[15];
    const float* b2   = (const float*)d_in[16];
    const unsigned char* pad = (const unsigned char*)d_in[17];

    char* ws = (char*)d_ws;
    const size_t MB = 1024 * 1024;
    bf16_t* WqkvT = (bf16_t*)(ws + 0 * MB);   // 6MB  [dead after QKV]
    bf16_t* WoT = (bf16_t*)(ws + 6 * MB);     // 2MB  [dead after O-proj]
    bf16_t* W1T = (bf16_t*)(ws + 8 * MB);     // 8MB  [dead after GELU]
    bf16_t* W2T = (bf16_t*)(ws + 16 * MB);    // 8MB  [dead after W2]
    bf16_t* h   = (bf16_t*)(ws + 24 * MB);    // 8MB  [dead after QKV]
    bf16_t* qb  = (bf16_t*)(ws + 32 * MB);    // 8MB  [dead after attn]
    bf16_t* kb  = (bf16_t*)(ws + 40 * MB);    // 8MB  [dead after attn]
    bf16_t* vb  = (bf16_t*)(ws + 48 * MB);    // 8MB  [dead after attn] (V^T)
    bf16_t* ob  = (bf16_t*)(ws + 56 * MB);    // 8MB  [dead after O-proj]
    bf16_t* ppO = (bf16_t*)(ws + 24 * MB);    // 4x8MB @24-56 [O-proj partials]
    bf16_t* m2  = (bf16_t*)(ws + 56 * MB);    // 8MB  @56-64 [dead after GELU]
    bf16_t* x2  = (bf16_t*)(ws + 64 * MB);    // 8MB  @64-72 [alive to end, bf16]
    bf16_t* hid = (bf16_t*)(ws + 24 * MB);    // 32MB @24-56 [dead after W2]
    bf16_t* pW01 = (bf16_t*)(ws + 0 * MB);    // 2x8MB @0-16
    bf16_t* pW23 = (bf16_t*)(ws + 80 * MB);   // 2x8MB @80-96

    const long long ZS = 4ll * 1024 * 1024;

    const dim3 blk(256);
    const dim3 blk8(512);
    // small weight transposes + LN1 (W1/W2 transposes moved into attn grid)
    k_prep<<<8192, blk, 0, stream>>>(
        Wq, Wk, Wv, Wo,
        WqkvT, WqkvT + 1024 * 1024, WqkvT + 2048 * 1024, WoT,
        x, ln1g, ln1b, h);
    // fused QKV projection: 768 blocks (3/CU), ring + supertile
    k_gemm2<EPI_QKV><<<dim3(24, 32), blk, 0, stream>>>(
        h, WqkvT, bq, bk, bv, qb, kb, vb, 4096, 3072, 1024, 1024, 0);
    // attention (1024 blocks, LPT) + W1/W2 transposes (8192 filler blocks)
    k_attn<<<9216, blk, 0, stream>>>(qb, kb, vb, pad, ob, W1, W2, W1T, W2T);
    // O-proj split-K x4: 1024 blocks, Ksub=256; bf16 partials @24-56
    k_gemm2<EPI_PARTB><<<dim3(8, 32, 4), blk, 0, stream>>>(
        ob, WoT, nullptr, nullptr, nullptr, ppO, ppO + 2 * ZS, nullptr,
        4096, 1024, 256, 1024, ZS);
    // reduce 4 partials + bias + residual + LN2 -> x2 (bf16), m2 (bf16)
    k_reduce_ln4<<<4096, blk, 0, stream>>>(ppO, bo, x, ln2g, ln2b, x2, m2, ZS);
    // MLP up + GELU: 256-sq staggered 2-phase + supertile, 256 blocks
    k_gemm256<EPI_GELU><<<dim3(16, 16), blk8, 0, stream>>>(
        m2, W1T, b1, hid, nullptr, 4096, 4096, 1024, 1024, 0);
    // MLP down split-K x4: 256-sq staggered 2-phase + supertile, 256 blocks
    k_gemm256<EPI_PARTB><<<dim3(4, 16, 4), blk8, 0, stream>>>(
        hid, W2T, nullptr, pW01, pW23, 4096, 1024, 1024, 4096, ZS);
    // final reduce: d_out = pW01(2) + pW23(2) + b2 + x2
    k_reduce_out4<<<4096, blk, 0, stream>>>(pW01, pW23, b2, x2, (float*)d_out, ZS);
}